// Round 6
// baseline (182.706 us; speedup 1.0000x reference)
//
#include <hip/hip_runtime.h>
#include <hip/hip_bf16.h>

// Joiner: logits[n,t,u,v] = sum_d tanh(enc[n,t,d]+dec[n,u,d]) * W[v,d] + b[v]
// N=8 T=200 U=100 D=512 V=500  -> GEMM M=160000, K=512, N=500 (padded 512)
//
// R5: R2 skeleton (BM=64, BN=512, 256 thr, dbuf-LDS A, 1 barrier/K-step,
// direct-B global->VGPR) switched to mfma_f32_32x32x16_bf16. The 32x32 C
// layout (col=lane&31, row=(reg&3)+8*(reg>>2)+4*(lane>>5)) makes each acc
// reg a contiguous 32-col span -> DIRECT global stores (2x128B segments per
// instr), deleting the LDS epilogue and all its barriers.

#define NB 8
#define TT 200
#define UU 100
#define DD 512
#define VV 500
#define VP 512
#define BM 64
#define BK 32
#define KSTEPS 16          // 512/32
#define THREADS 256
#define LDA 36             // BK + 4 pad (ushort units, 72B row stride)
#define MROWS (NB*TT*UU)   // 160000
#define MBLOCKS (MROWS/BM) // 2500

typedef __attribute__((ext_vector_type(4)))  float f32x4;
typedef __attribute__((ext_vector_type(16))) float f32x16;
typedef __attribute__((ext_vector_type(8)))  short s16x8;

__device__ __forceinline__ unsigned short f2bf(float f) {
    unsigned int u = __builtin_bit_cast(unsigned int, f);
    u = (u + 0x7FFFu + ((u >> 16) & 1u)) >> 16;   // round-to-nearest-even
    return (unsigned short)u;
}

__device__ __forceinline__ float fast_tanh(float x) {
    float e = __expf(2.0f * x);
    return 1.0f - 2.0f * __builtin_amdgcn_rcpf(e + 1.0f);
}

// ---- prep: W (500x512 f32) -> bf16, padded, tiled for 32x32x16 B-frags ----
// Layout: block b = (kc*16 + vb)*2 + kh  (kc: 32-k chunk, vb: 32-col block,
// kh: 16-k half). Within block: ((oct*32 + c)*8 + j) where lane = oct*32+c
// reads 16B contiguous -> 1KB per wave fragment load.
__global__ void prep_w(const float* __restrict__ W, unsigned short* __restrict__ Wt) {
    int idx = blockIdx.x * 256 + threadIdx.x;   // 0 .. 512*512-1
    int k = idx & 511;
    int v = idx >> 9;
    float val = (v < VV) ? W[v * DD + k] : 0.0f;
    int kc  = k >> 5;
    int kh  = (k >> 4) & 1;
    int oct = (k >> 3) & 1;
    int j   = k & 7;
    int vb  = v >> 5;
    int c   = v & 31;
    Wt[((((kc << 4) + vb) << 1) + kh) * 512 + ((oct << 5) + c) * 8 + j] = f2bf(val);
}

__global__ __launch_bounds__(THREADS, 2) void joiner_kernel(
    const float* __restrict__ enc, const float* __restrict__ dec,
    const unsigned short* __restrict__ Wt, const float* __restrict__ bias,
    float* __restrict__ out)
{
    __shared__ unsigned short lA[2][BM * LDA];   // 2 x 4608 B

    const int tid  = threadIdx.x;
    const int mb   = blockIdx.x;
    const int lane = tid & 63;
    const int wn   = tid >> 6;       // 0..3: 128-col quarter
    const int lr31 = lane & 31;      // A row within 32-row frag / C col
    const int oct  = lane >> 5;      // k-octet selector

    // staging: each thread produces 8 activations of one row
    const int srow = tid >> 2;          // 0..63
    const int sk   = (tid & 3) << 3;    // 0,8,16,24

    int r   = mb * BM + srow;
    int n   = r / (TT * UU);
    int rem = r - n * (TT * UU);
    int t   = rem / UU;
    int u   = rem - t * UU;
    const float* ep = enc + (n * TT + t) * DD + sk;
    const float* dp = dec + (n * UU + u) * DD + sk;

    f32x4 e0, e1, d0, d1;

    // ---- stage kc=0 ----
    e0 = *(const f32x4*)(ep);     e1 = *(const f32x4*)(ep + 4);
    d0 = *(const f32x4*)(dp);     d1 = *(const f32x4*)(dp + 4);
    {
        s16x8 av;
        #pragma unroll
        for (int j = 0; j < 4; ++j) av[j]     = (short)f2bf(fast_tanh(e0[j] + d0[j]));
        #pragma unroll
        for (int j = 0; j < 4; ++j) av[4 + j] = (short)f2bf(fast_tanh(e1[j] + d1[j]));
        *(s16x8*)(&lA[0][srow * LDA + sk]) = av;
    }
    // ---- prefetch kc=1 into regs ----
    e0 = *(const f32x4*)(ep + BK);     e1 = *(const f32x4*)(ep + BK + 4);
    d0 = *(const f32x4*)(dp + BK);     d1 = *(const f32x4*)(dp + BK + 4);
    __syncthreads();

    f32x16 acc[2][4];
    #pragma unroll
    for (int rf = 0; rf < 2; ++rf)
        #pragma unroll
        for (int cf = 0; cf < 4; ++cf)
            #pragma unroll
            for (int q = 0; q < 16; ++q)
                acc[rf][cf][q] = 0.0f;

    for (int kc = 0; kc < KSTEPS; ++kc) {
        const unsigned short* lCur = lA[kc & 1];
        unsigned short*       lNxt = lA[(kc + 1) & 1];

        // ---- B fragments: direct global->VGPR (L1/L2-hit, 1KB contiguous) ----
        s16x8 bF[4][2];
        #pragma unroll
        for (int cf = 0; cf < 4; ++cf)
            #pragma unroll
            for (int kh = 0; kh < 2; ++kh)
                bF[cf][kh] = *(const s16x8*)(
                    Wt + ((((kc << 4) + (wn << 2) + cf) << 1) + kh) * 512 + (lane << 3));

        // ---- A fragments from LDS: row rf*32+lr31, k = kh*16 + oct*8 ----
        s16x8 aF[2][2];
        #pragma unroll
        for (int rf = 0; rf < 2; ++rf)
            #pragma unroll
            for (int kh = 0; kh < 2; ++kh)
                aF[rf][kh] = *(const s16x8*)(
                    &lCur[(rf * 32 + lr31) * LDA + kh * 16 + oct * 8]);

        // ---- stage next A tile, then prefetch the one after into regs ----
        if (kc < KSTEPS - 1) {
            s16x8 av;
            #pragma unroll
            for (int j = 0; j < 4; ++j) av[j]     = (short)f2bf(fast_tanh(e0[j] + d0[j]));
            #pragma unroll
            for (int j = 0; j < 4; ++j) av[4 + j] = (short)f2bf(fast_tanh(e1[j] + d1[j]));
            *(s16x8*)(&lNxt[srow * LDA + sk]) = av;
            if (kc < KSTEPS - 2) {
                const float* ep2 = ep + (kc + 2) * BK;
                const float* dp2 = dp + (kc + 2) * BK;
                e0 = *(const f32x4*)(ep2);     e1 = *(const f32x4*)(ep2 + 4);
                d0 = *(const f32x4*)(dp2);     d1 = *(const f32x4*)(dp2 + 4);
            }
        }

        // ---- 16 MFMAs (32x32x16, ~2x FLOP each) ----
        __builtin_amdgcn_s_setprio(1);
        #pragma unroll
        for (int kh = 0; kh < 2; ++kh)
            #pragma unroll
            for (int rf = 0; rf < 2; ++rf)
                #pragma unroll
                for (int cf = 0; cf < 4; ++cf)
                    acc[rf][cf] = __builtin_amdgcn_mfma_f32_32x32x16_bf16(
                        aF[rf][kh], bF[cf][kh], acc[rf][cf], 0, 0, 0);
        __builtin_amdgcn_s_setprio(0);

        if (kc < KSTEPS - 1) __syncthreads();
    }

    // ---- epilogue: bias + DIRECT stores (each reg = 32 contiguous cols) ----
    const long rowbase = (long)mb * BM;
    #pragma unroll
    for (int cf = 0; cf < 4; ++cf) {
        int col = (wn << 7) + (cf << 5) + lr31;
        if (col < VV) {
            float bv = bias[col];
            #pragma unroll
            for (int rf = 0; rf < 2; ++rf) {
                float* pbase = out + (rowbase + rf * 32 + 4 * oct) * VV + col;
                #pragma unroll
                for (int reg = 0; reg < 16; ++reg) {
                    int rofs = (reg & 3) + 8 * (reg >> 2);   // + 4*oct folded above
                    pbase[(long)rofs * VV] = acc[rf][cf][reg] + bv;
                }
            }
        }
    }
}

extern "C" void kernel_launch(void* const* d_in, const int* in_sizes, int n_in,
                              void* d_out, int out_size, void* d_ws, size_t ws_size,
                              hipStream_t stream) {
    const float* enc = (const float*)d_in[0];
    const float* dec = (const float*)d_in[1];
    const float* W   = (const float*)d_in[2];
    const float* b   = (const float*)d_in[3];
    float* out = (float*)d_out;
    unsigned short* Wt = (unsigned short*)d_ws;   // 512*512*2 = 512 KB

    prep_w<<<dim3((VP * DD) / 256), dim3(256), 0, stream>>>(W, Wt);
    joiner_kernel<<<dim3(MBLOCKS), dim3(THREADS), 0, stream>>>(enc, dec, Wt, b, out);
}